// Round 1
// baseline (596.967 us; speedup 1.0000x reference)
//
#include <hip/hip_runtime.h>

#define N_NODES 50000
#define N_EDGES 800000
#define SCAN_BLOCKS 196          // ceil(50000/256)

// ---------------- workspace layout (bytes) ----------------
// cnt      int[N]      @ 0x000000
// rowstart int[N+1]    @ 0x040000
// cursor   int[N]      @ 0x080000
// bsum     int[256]    @ 0x0C0000
// bprefix  int[256]    @ 0x0C1000
// csr_src  int[E]      @ 0x100000  (3.2 MB)
// mean     f32[N*128]  @ 0x500000  (25.6 MB)
// h        f32[N*128]  @ 0x2000000 (25.6 MB)  -> total ~57.6 MB

// ---------------- CSR build ----------------
__global__ void count_edges(const int* __restrict__ ei, int* __restrict__ cnt) {
    int e = blockIdx.x * 256 + threadIdx.x;
    if (e < N_EDGES) atomicAdd(&cnt[ei[N_EDGES + e]], 1);
}

__global__ void block_sums(const int* __restrict__ cnt, int* __restrict__ bsum) {
    int i = blockIdx.x * 256 + threadIdx.x;
    int v = (i < N_NODES) ? cnt[i] : 0;
    for (int off = 32; off; off >>= 1) v += __shfl_down(v, off, 64);
    __shared__ int s[4];
    if ((threadIdx.x & 63) == 0) s[threadIdx.x >> 6] = v;
    __syncthreads();
    if (threadIdx.x == 0) bsum[blockIdx.x] = s[0] + s[1] + s[2] + s[3];
}

__global__ void scan_bsums(const int* __restrict__ bsum, int* __restrict__ bprefix,
                           int* __restrict__ rowstart) {
    __shared__ int s[256];
    int t = threadIdx.x;
    int v = (t < SCAN_BLOCKS) ? bsum[t] : 0;
    s[t] = v;
    __syncthreads();
    for (int off = 1; off < 256; off <<= 1) {
        int add = (t >= off) ? s[t - off] : 0;
        __syncthreads();
        s[t] += add;
        __syncthreads();
    }
    bprefix[t] = s[t] - v;                 // exclusive prefix of block sums
    if (t == 0) rowstart[N_NODES] = N_EDGES;
}

__global__ void apply_scan(const int* __restrict__ cnt, const int* __restrict__ bprefix,
                           int* __restrict__ rowstart, int* __restrict__ cursor) {
    __shared__ int s[256];
    int t = threadIdx.x;
    int i = blockIdx.x * 256 + t;
    int v = (i < N_NODES) ? cnt[i] : 0;
    s[t] = v;
    __syncthreads();
    for (int off = 1; off < 256; off <<= 1) {
        int add = (t >= off) ? s[t - off] : 0;
        __syncthreads();
        s[t] += add;
        __syncthreads();
    }
    int excl = s[t] - v + bprefix[blockIdx.x];
    if (i < N_NODES) { rowstart[i] = excl; cursor[i] = excl; }
}

__global__ void fill_csr(const int* __restrict__ ei, int* __restrict__ cursor,
                         int* __restrict__ csr_src) {
    int e = blockIdx.x * 256 + threadIdx.x;
    if (e < N_EDGES) {
        int d = ei[N_EDGES + e];
        int p = atomicAdd(&cursor[d], 1);
        csr_src[p] = ei[e];
    }
}

// ---------------- mean aggregation: one wave per node, 2 floats/lane ----------------
__global__ void aggregate(const float* __restrict__ h, const int* __restrict__ rowstart,
                          const int* __restrict__ csr_src, float* __restrict__ mean) {
    int node = blockIdx.x * 4 + (threadIdx.x >> 6);
    int lane = threadIdx.x & 63;
    if (node >= N_NODES) return;
    int s0 = rowstart[node], s1 = rowstart[node + 1];
    float ax = 0.f, ay = 0.f;
    const float2* base = (const float2*)h;
    for (int i = s0; i < s1; ++i) {
        int s = csr_src[i];
        float2 v = base[(size_t)s * 64 + lane];
        ax += v.x; ay += v.y;
    }
    float inv = 1.0f / fmaxf((float)(s1 - s0), 1.0f);
    float2 o; o.x = ax * inv; o.y = ay * inv;
    ((float2*)mean)[(size_t)node * 64 + lane] = o;
}

// ---------------- fused SAGE GEMM: out = mean@Wl + hin@Wr + b (stacked K=256) ----------------
template <int DO, bool RELU>
__global__ __launch_bounds__(256) void sage_gemm(
    const float* __restrict__ mean, const float* __restrict__ hin,
    const float* __restrict__ Wl, const float* __restrict__ Wr,
    const float* __restrict__ bias, float* __restrict__ out) {
    constexpr int TN = (DO == 128) ? 8 : 4;  // 16 col-groups either way
    constexpr int KB = 16;
    __shared__ float Ash[KB][64];
    __shared__ float Wsh[KB][DO];
    int tid = threadIdx.x;
    int rowBase = blockIdx.x * 64;
    int rg = tid / 16, cg = tid % 16;
    int m0 = rg * 4, j0 = cg * TN;
    float acc[4][TN];
    #pragma unroll
    for (int r = 0; r < 4; ++r)
        #pragma unroll
        for (int c = 0; c < TN; ++c) acc[r][c] = 0.f;

    for (int k0 = 0; k0 < 256; k0 += KB) {
        // stage A chunk (64 rows x 16 k), transposed into LDS
        {
            int row = tid >> 2;
            int kk = (tid & 3) * 4;
            int rowg = min(rowBase + row, N_NODES - 1);
            const float* src = (k0 < 128) ? (mean + (size_t)rowg * 128 + k0 + kk)
                                          : (hin + (size_t)rowg * 128 + (k0 - 128) + kk);
            float4 a = *(const float4*)src;
            Ash[kk + 0][row] = a.x;
            Ash[kk + 1][row] = a.y;
            Ash[kk + 2][row] = a.z;
            Ash[kk + 3][row] = a.w;
        }
        // stage W chunk (16 x DO) from stacked [Wl; Wr]
        {
            constexpr int NV = KB * DO / 4;
            #pragma unroll
            for (int v = 0; v < NV; v += 256) {
                int idx = v + tid;
                int k = idx / (DO / 4);
                int j = (idx % (DO / 4)) * 4;
                int kg = k0 + k;
                const float* wsrc = (kg < 128) ? (Wl + (size_t)kg * DO + j)
                                               : (Wr + (size_t)(kg - 128) * DO + j);
                *(float4*)&Wsh[k][j] = *(const float4*)wsrc;
            }
        }
        __syncthreads();
        #pragma unroll
        for (int kk = 0; kk < KB; ++kk) {
            float a[4], w[TN];
            *(float4*)a = *(const float4*)&Ash[kk][m0];
            #pragma unroll
            for (int t = 0; t < TN; t += 4)
                *(float4*)&w[t] = *(const float4*)&Wsh[kk][j0 + t];
            #pragma unroll
            for (int r = 0; r < 4; ++r)
                #pragma unroll
                for (int c = 0; c < TN; ++c)
                    acc[r][c] += a[r] * w[c];
        }
        __syncthreads();
    }
    // epilogue: bias (+ReLU), vectorized store
    #pragma unroll
    for (int r = 0; r < 4; ++r) {
        int row = rowBase + m0 + r;
        if (row < N_NODES) {
            #pragma unroll
            for (int t = 0; t < TN; t += 4) {
                float4 o;
                o.x = acc[r][t + 0] + bias[j0 + t + 0];
                o.y = acc[r][t + 1] + bias[j0 + t + 1];
                o.z = acc[r][t + 2] + bias[j0 + t + 2];
                o.w = acc[r][t + 3] + bias[j0 + t + 3];
                if (RELU) {
                    o.x = fmaxf(o.x, 0.f); o.y = fmaxf(o.y, 0.f);
                    o.z = fmaxf(o.z, 0.f); o.w = fmaxf(o.w, 0.f);
                }
                *(float4*)&out[(size_t)row * DO + j0 + t] = o;
            }
        }
    }
}

// ---------------- log_softmax over 64 cols: one wave per row ----------------
__global__ void logsoftmax_k(const float* __restrict__ h, float* __restrict__ out) {
    int row = blockIdx.x * 4 + (threadIdx.x >> 6);
    int lane = threadIdx.x & 63;
    if (row >= N_NODES) return;
    float v = h[(size_t)row * 64 + lane];
    float m = v;
    for (int off = 32; off; off >>= 1) m = fmaxf(m, __shfl_xor(m, off, 64));
    float e = expf(v - m);
    float s = e;
    for (int off = 32; off; off >>= 1) s += __shfl_xor(s, off, 64);
    out[(size_t)row * 64 + lane] = (v - m) - logf(s);
}

extern "C" void kernel_launch(void* const* d_in, const int* in_sizes, int n_in,
                              void* d_out, int out_size, void* d_ws, size_t ws_size,
                              hipStream_t stream) {
    const float* x  = (const float*)d_in[0];
    const int* ei   = (const int*)d_in[1];
    const float* Wl0 = (const float*)d_in[2];
    const float* Wr0 = (const float*)d_in[3];
    const float* b0  = (const float*)d_in[4];
    const float* Wl1 = (const float*)d_in[5];
    const float* Wr1 = (const float*)d_in[6];
    const float* b1  = (const float*)d_in[7];
    const float* Wl2 = (const float*)d_in[8];
    const float* Wr2 = (const float*)d_in[9];
    const float* b2  = (const float*)d_in[10];
    float* out = (float*)d_out;

    char* ws = (char*)d_ws;
    int* cnt      = (int*)(ws + 0x000000);
    int* rowstart = (int*)(ws + 0x040000);
    int* cursor   = (int*)(ws + 0x080000);
    int* bsum     = (int*)(ws + 0x0C0000);
    int* bprefix  = (int*)(ws + 0x0C1000);
    int* csr_src  = (int*)(ws + 0x100000);
    float* mean   = (float*)(ws + 0x500000);
    float* h      = (float*)(ws + 0x2000000);

    // ---- CSR build (once per call) ----
    hipMemsetAsync(cnt, 0, N_NODES * sizeof(int), stream);
    count_edges<<<3125, 256, 0, stream>>>(ei, cnt);
    block_sums<<<SCAN_BLOCKS, 256, 0, stream>>>(cnt, bsum);
    scan_bsums<<<1, 256, 0, stream>>>(bsum, bprefix, rowstart);
    apply_scan<<<SCAN_BLOCKS, 256, 0, stream>>>(cnt, bprefix, rowstart, cursor);
    fill_csr<<<3125, 256, 0, stream>>>(ei, cursor, csr_src);

    // ---- layer 0: x -> h (ReLU) ----
    aggregate<<<12500, 256, 0, stream>>>(x, rowstart, csr_src, mean);
    sage_gemm<128, true><<<782, 256, 0, stream>>>(mean, x, Wl0, Wr0, b0, h);

    // ---- layer 1: h -> h (ReLU, in-place safe: blocks touch only own rows) ----
    aggregate<<<12500, 256, 0, stream>>>(h, rowstart, csr_src, mean);
    sage_gemm<128, true><<<782, 256, 0, stream>>>(mean, h, Wl1, Wr1, b1, h);

    // ---- layer 2: h -> d_out second half (no ReLU) ----
    aggregate<<<12500, 256, 0, stream>>>(h, rowstart, csr_src, mean);
    float* hout = out + (size_t)N_NODES * 64;   // 3,200,000
    sage_gemm<64, false><<<782, 256, 0, stream>>>(mean, h, Wl2, Wr2, b2, hout);

    // ---- log_softmax -> d_out first half ----
    logsoftmax_k<<<12500, 256, 0, stream>>>(hout, out);
}

// Round 2
// 366.796 us; speedup vs baseline: 1.6275x; 1.6275x over previous
//
#include <hip/hip_runtime.h>

#define N_NODES 50000
#define N_EDGES 800000
#define SCAN_BLOCKS 196          // ceil(50000/256)

typedef __attribute__((ext_vector_type(8))) short short8;
typedef __attribute__((ext_vector_type(4))) float f32x4;
typedef unsigned short ushort_t;
typedef unsigned int uint_t;

// ---------------- helpers ----------------
__device__ inline ushort_t f2bf(float f) {
    union { float f; uint_t u; } v; v.f = f;
    uint_t u = v.u;
    u += 0x7fffu + ((u >> 16) & 1u);   // RNE
    return (ushort_t)(u >> 16);
}
__device__ inline float bflo(uint_t v) { return __uint_as_float(v << 16); }
__device__ inline float bfhi(uint_t v) { return __uint_as_float(v & 0xffff0000u); }

// ---------------- CSR build ----------------
__global__ void count_edges(const int* __restrict__ ei, int* __restrict__ cnt) {
    int e = blockIdx.x * 256 + threadIdx.x;
    if (e < N_EDGES) atomicAdd(&cnt[ei[N_EDGES + e]], 1);
}

__global__ void block_sums(const int* __restrict__ cnt, int* __restrict__ bsum) {
    int i = blockIdx.x * 256 + threadIdx.x;
    int v = (i < N_NODES) ? cnt[i] : 0;
    for (int off = 32; off; off >>= 1) v += __shfl_down(v, off, 64);
    __shared__ int s[4];
    if ((threadIdx.x & 63) == 0) s[threadIdx.x >> 6] = v;
    __syncthreads();
    if (threadIdx.x == 0) bsum[blockIdx.x] = s[0] + s[1] + s[2] + s[3];
}

__global__ void scan_bsums(const int* __restrict__ bsum, int* __restrict__ bprefix,
                           int* __restrict__ rowstart) {
    __shared__ int s[256];
    int t = threadIdx.x;
    int v = (t < SCAN_BLOCKS) ? bsum[t] : 0;
    s[t] = v;
    __syncthreads();
    for (int off = 1; off < 256; off <<= 1) {
        int add = (t >= off) ? s[t - off] : 0;
        __syncthreads();
        s[t] += add;
        __syncthreads();
    }
    bprefix[t] = s[t] - v;
    if (t == 0) rowstart[N_NODES] = N_EDGES;
}

__global__ void apply_scan(const int* __restrict__ cnt, const int* __restrict__ bprefix,
                           int* __restrict__ rowstart, int* __restrict__ cursor) {
    __shared__ int s[256];
    int t = threadIdx.x;
    int i = blockIdx.x * 256 + t;
    int v = (i < N_NODES) ? cnt[i] : 0;
    s[t] = v;
    __syncthreads();
    for (int off = 1; off < 256; off <<= 1) {
        int add = (t >= off) ? s[t - off] : 0;
        __syncthreads();
        s[t] += add;
        __syncthreads();
    }
    int excl = s[t] - v + bprefix[blockIdx.x];
    if (i < N_NODES) { rowstart[i] = excl; cursor[i] = excl; }
}

__global__ void fill_csr(const int* __restrict__ ei, int* __restrict__ cursor,
                         int* __restrict__ csr_src) {
    int e = blockIdx.x * 256 + threadIdx.x;
    if (e < N_EDGES) {
        int d = ei[N_EDGES + e];
        int p = atomicAdd(&cursor[d], 1);
        csr_src[p] = ei[e];
    }
}

// ---------------- fp32 -> bf16 conversion (x only) ----------------
__global__ void cvt_bf16(const float* __restrict__ in, ushort_t* __restrict__ out, int n4) {
    int i = blockIdx.x * 256 + threadIdx.x;
    if (i < n4) {
        float4 v = ((const float4*)in)[i];
        ushort4 o;
        o.x = f2bf(v.x); o.y = f2bf(v.y); o.z = f2bf(v.z); o.w = f2bf(v.w);
        ((ushort4*)out)[i] = o;
    }
}

// ---------------- mean aggregation (bf16 rows, 4-wide MLP unroll) ----------------
// one wave per node; lane holds 2 of 128 dims (uint = bfloat162)
__global__ void aggregate_bf(const ushort_t* __restrict__ hbf,
                             const int* __restrict__ rowstart,
                             const int* __restrict__ csr_src,
                             ushort_t* __restrict__ meanbf) {
    int node = blockIdx.x * 4 + (threadIdx.x >> 6);
    int lane = threadIdx.x & 63;
    if (node >= N_NODES) return;
    int s0 = rowstart[node], s1 = rowstart[node + 1];
    float ax = 0.f, ay = 0.f;
    const uint_t* base = (const uint_t*)hbf;
    for (int b = s0; b < s1; b += 64) {
        int m = min(64, s1 - b);
        int idx = (lane < m) ? csr_src[b + lane] : 0;
        int j = 0;
        for (; j + 4 <= m; j += 4) {
            int i0 = __shfl(idx, j, 64);
            int i1 = __shfl(idx, j + 1, 64);
            int i2 = __shfl(idx, j + 2, 64);
            int i3 = __shfl(idx, j + 3, 64);
            uint_t v0 = base[(size_t)i0 * 64 + lane];
            uint_t v1 = base[(size_t)i1 * 64 + lane];
            uint_t v2 = base[(size_t)i2 * 64 + lane];
            uint_t v3 = base[(size_t)i3 * 64 + lane];
            ax += bflo(v0) + bflo(v1) + bflo(v2) + bflo(v3);
            ay += bfhi(v0) + bfhi(v1) + bfhi(v2) + bfhi(v3);
        }
        for (; j < m; ++j) {
            uint_t v = base[(size_t)__shfl(idx, j, 64) * 64 + lane];
            ax += bflo(v);
            ay += bfhi(v);
        }
    }
    float inv = 1.0f / fmaxf((float)(s1 - s0), 1.0f);
    ax *= inv; ay *= inv;
    uint_t packed = (uint_t)f2bf(ax) | ((uint_t)f2bf(ay) << 16);
    ((uint_t*)meanbf)[(size_t)node * 64 + lane] = packed;
}

// ---------------- bf16 MFMA GEMM: out = [mean|root] @ [Wl;Wr] + b ----------------
// Block: 4 waves, 64 rows. Wave computes 16 rows x DO cols via 16x16x32 MFMA.
// Stacked weights (256 x DO) staged transposed in LDS as bf16.
// FINAL: DO=64, fuse log_softmax; write d_out[0:N*64]=log_softmax, [N*64:]=h.
template <int DO, bool RELU, bool FINAL>
__global__ __launch_bounds__(256, 2) void sage_gemm_mfma(
    const ushort_t* __restrict__ mean_bf, const ushort_t* __restrict__ root_bf,
    const float* __restrict__ Wl, const float* __restrict__ Wr,
    const float* __restrict__ bias,
    ushort_t* __restrict__ out_bf, float* __restrict__ out_f32) {
    constexpr int NT = DO / 16;            // column tiles per wave
    __shared__ ushort_t Wt[DO][264];       // [n][k], pad to 264 (16B-aligned rows, 2-way banks)

    // stage stacked weights, transposed, fp32->bf16
    constexpr int TOT = 256 * DO;
    for (int idx = threadIdx.x; idx < TOT; idx += 256) {
        int k = idx / DO, n = idx % DO;
        float w = (k < 128) ? Wl[k * DO + n] : Wr[(k - 128) * DO + n];
        Wt[n][k] = f2bf(w);
    }
    __syncthreads();

    int lane = threadIdx.x & 63;
    int wave = threadIdx.x >> 6;
    int row16 = lane & 15;
    int quad = lane >> 4;
    int rowBase = blockIdx.x * 64 + wave * 16;
    int arow = min(rowBase + row16, N_NODES - 1);
    const ushort_t* mrow = mean_bf + (size_t)arow * 128;
    const ushort_t* rrow = root_bf + (size_t)arow * 128;

    f32x4 acc[NT];
    #pragma unroll
    for (int t = 0; t < NT; ++t) { f32x4 z = {0.f, 0.f, 0.f, 0.f}; acc[t] = z; }

    #pragma unroll
    for (int ks = 0; ks < 8; ++ks) {
        int k0 = ks * 32;
        const ushort_t* src = (k0 < 128) ? (mrow + k0 + quad * 8)
                                         : (rrow + (k0 - 128) + quad * 8);
        short8 afrag = *(const short8*)src;
        #pragma unroll
        for (int t = 0; t < NT; ++t) {
            int n = t * 16 + row16;
            short8 bfrag = *(const short8*)&Wt[n][k0 + quad * 8];
            acc[t] = __builtin_amdgcn_mfma_f32_16x16x32_bf16(afrag, bfrag, acc[t], 0, 0, 0);
        }
    }

    // epilogue; D layout: row_local = quad*4 + reg, col = t*16 + row16
    if (!FINAL) {
        #pragma unroll
        for (int t = 0; t < NT; ++t) {
            int col = t * 16 + row16;
            float bv = bias[col];
            #pragma unroll
            for (int r = 0; r < 4; ++r) {
                int row = rowBase + quad * 4 + r;
                if (row < N_NODES) {
                    float v = acc[t][r] + bv;
                    if (RELU) v = fmaxf(v, 0.f);
                    out_bf[(size_t)row * DO + col] = f2bf(v);
                }
            }
        }
    } else {
        // one wave holds 16 full 64-wide rows: row r's values live in one quad
        float val[NT][4];
        #pragma unroll
        for (int t = 0; t < NT; ++t) {
            float bv = bias[t * 16 + row16];
            #pragma unroll
            for (int r = 0; r < 4; ++r) val[t][r] = acc[t][r] + bv;
        }
        #pragma unroll
        for (int r = 0; r < 4; ++r) {
            float m = val[0][r];
            #pragma unroll
            for (int t = 1; t < NT; ++t) m = fmaxf(m, val[t][r]);
            for (int off = 1; off < 16; off <<= 1) m = fmaxf(m, __shfl_xor(m, off, 64));
            float s = 0.f;
            #pragma unroll
            for (int t = 0; t < NT; ++t) s += expf(val[t][r] - m);
            for (int off = 1; off < 16; off <<= 1) s += __shfl_xor(s, off, 64);
            float lse = m + logf(s);
            int row = rowBase + quad * 4 + r;
            if (row < N_NODES) {
                #pragma unroll
                for (int t = 0; t < NT; ++t) {
                    int col = t * 16 + row16;
                    float h = val[t][r];
                    out_f32[(size_t)N_NODES * 64 + (size_t)row * 64 + col] = h;      // h
                    out_f32[(size_t)row * 64 + col] = h - lse;                        // log_softmax
                }
            }
        }
    }
}

extern "C" void kernel_launch(void* const* d_in, const int* in_sizes, int n_in,
                              void* d_out, int out_size, void* d_ws, size_t ws_size,
                              hipStream_t stream) {
    const float* x  = (const float*)d_in[0];
    const int* ei   = (const int*)d_in[1];
    const float* Wl0 = (const float*)d_in[2];
    const float* Wr0 = (const float*)d_in[3];
    const float* b0  = (const float*)d_in[4];
    const float* Wl1 = (const float*)d_in[5];
    const float* Wr1 = (const float*)d_in[6];
    const float* b1  = (const float*)d_in[7];
    const float* Wl2 = (const float*)d_in[8];
    const float* Wr2 = (const float*)d_in[9];
    const float* b2  = (const float*)d_in[10];
    float* out = (float*)d_out;

    char* ws = (char*)d_ws;
    int* cnt      = (int*)(ws + 0x000000);
    int* rowstart = (int*)(ws + 0x040000);
    int* cursor   = (int*)(ws + 0x080000);
    int* bsum     = (int*)(ws + 0x0C0000);
    int* bprefix  = (int*)(ws + 0x0C1000);
    int* csr_src  = (int*)(ws + 0x100000);
    ushort_t* x_bf   = (ushort_t*)(ws + 0x0500000);   // 12.8 MB
    ushort_t* mean_bf = (ushort_t*)(ws + 0x1200000);  // 12.8 MB
    ushort_t* h_bf   = (ushort_t*)(ws + 0x1F00000);   // 12.8 MB

    // ---- CSR build ----
    hipMemsetAsync(cnt, 0, N_NODES * sizeof(int), stream);
    count_edges<<<3125, 256, 0, stream>>>(ei, cnt);
    block_sums<<<SCAN_BLOCKS, 256, 0, stream>>>(cnt, bsum);
    scan_bsums<<<1, 256, 0, stream>>>(bsum, bprefix, rowstart);
    apply_scan<<<SCAN_BLOCKS, 256, 0, stream>>>(cnt, bprefix, rowstart, cursor);
    fill_csr<<<3125, 256, 0, stream>>>(ei, cursor, csr_src);

    // ---- x -> bf16 ----
    cvt_bf16<<<6250, 256, 0, stream>>>(x, x_bf, (N_NODES * 128) / 4);

    // ---- layer 0 ----
    aggregate_bf<<<12500, 256, 0, stream>>>(x_bf, rowstart, csr_src, mean_bf);
    sage_gemm_mfma<128, true, false><<<782, 256, 0, stream>>>(
        mean_bf, x_bf, Wl0, Wr0, b0, h_bf, nullptr);

    // ---- layer 1 (in-place h: each wave reads only rows it writes) ----
    aggregate_bf<<<12500, 256, 0, stream>>>(h_bf, rowstart, csr_src, mean_bf);
    sage_gemm_mfma<128, true, false><<<782, 256, 0, stream>>>(
        mean_bf, h_bf, Wl1, Wr1, b1, h_bf, nullptr);

    // ---- layer 2 + fused log_softmax -> d_out ----
    aggregate_bf<<<12500, 256, 0, stream>>>(h_bf, rowstart, csr_src, mean_bf);
    sage_gemm_mfma<64, false, true><<<782, 256, 0, stream>>>(
        mean_bf, h_bf, Wl2, Wr2, b2, nullptr, out);
}

// Round 3
// 355.918 us; speedup vs baseline: 1.6773x; 1.0306x over previous
//
#include <hip/hip_runtime.h>

#define N_NODES 50000
#define N_EDGES 800000
#define SCAN_BLOCKS 196          // ceil(50000/256)
#define WIN 6250                 // dst window per XCD group (50000/8)

typedef __attribute__((ext_vector_type(8))) short short8;
typedef __attribute__((ext_vector_type(4))) float f32x4;
typedef unsigned short ushort_t;
typedef unsigned int uint_t;

// ---------------- helpers ----------------
__device__ inline ushort_t f2bf(float f) {
    union { float f; uint_t u; } v; v.f = f;
    uint_t u = v.u;
    u += 0x7fffu + ((u >> 16) & 1u);   // RNE
    return (ushort_t)(u >> 16);
}
__device__ inline float bflo(uint_t v) { return __uint_as_float(v << 16); }
__device__ inline float bfhi(uint_t v) { return __uint_as_float(v & 0xffff0000u); }
__device__ inline float bf2f(ushort_t v) { return __uint_as_float((uint_t)v << 16); }

// ---------------- CSR build: XCD-windowed counting sort ----------------
// blockIdx&7 ~ XCD id (round-robin dispatch heuristic): all atomics/stores for
// dst window g come from one XCD's L2 -> scattered 4B stores merge into lines.
__global__ void count_edges_mp(const int* __restrict__ ei, int* __restrict__ cnt) {
    int g = blockIdx.x & 7;
    int nb = gridDim.x >> 3;
    int bi = blockIdx.x >> 3;
    int lo = g * WIN;
    for (int e = bi * 256 + threadIdx.x; e < N_EDGES; e += nb * 256) {
        int d = ei[N_EDGES + e];
        if ((unsigned)(d - lo) < WIN) atomicAdd(&cnt[d], 1);
    }
}

__global__ void fill_csr_mp(const int* __restrict__ ei, int* __restrict__ cursor,
                            int* __restrict__ csr_src) {
    int g = blockIdx.x & 7;
    int nb = gridDim.x >> 3;
    int bi = blockIdx.x >> 3;
    int lo = g * WIN;
    for (int e = bi * 256 + threadIdx.x; e < N_EDGES; e += nb * 256) {
        int d = ei[N_EDGES + e];
        if ((unsigned)(d - lo) < WIN) {
            int p = atomicAdd(&cursor[d], 1);
            csr_src[p] = ei[e];
        }
    }
}

__global__ void block_sums(const int* __restrict__ cnt, int* __restrict__ bsum) {
    int i = blockIdx.x * 256 + threadIdx.x;
    int v = (i < N_NODES) ? cnt[i] : 0;
    for (int off = 32; off; off >>= 1) v += __shfl_down(v, off, 64);
    __shared__ int s[4];
    if ((threadIdx.x & 63) == 0) s[threadIdx.x >> 6] = v;
    __syncthreads();
    if (threadIdx.x == 0) bsum[blockIdx.x] = s[0] + s[1] + s[2] + s[3];
}

__global__ void scan_bsums(const int* __restrict__ bsum, int* __restrict__ bprefix,
                           int* __restrict__ rowstart) {
    __shared__ int s[256];
    int t = threadIdx.x;
    int v = (t < SCAN_BLOCKS) ? bsum[t] : 0;
    s[t] = v;
    __syncthreads();
    for (int off = 1; off < 256; off <<= 1) {
        int add = (t >= off) ? s[t - off] : 0;
        __syncthreads();
        s[t] += add;
        __syncthreads();
    }
    bprefix[t] = s[t] - v;
    if (t == 0) rowstart[N_NODES] = N_EDGES;
}

__global__ void apply_scan(const int* __restrict__ cnt, const int* __restrict__ bprefix,
                           int* __restrict__ rowstart, int* __restrict__ cursor) {
    __shared__ int s[256];
    int t = threadIdx.x;
    int i = blockIdx.x * 256 + t;
    int v = (i < N_NODES) ? cnt[i] : 0;
    s[t] = v;
    __syncthreads();
    for (int off = 1; off < 256; off <<= 1) {
        int add = (t >= off) ? s[t - off] : 0;
        __syncthreads();
        s[t] += add;
        __syncthreads();
    }
    int excl = s[t] - v + bprefix[blockIdx.x];
    if (i < N_NODES) { rowstart[i] = excl; cursor[i] = excl; }
}

// ---------------- fp32 -> bf16 conversion (x only) ----------------
__global__ void cvt_bf16(const float* __restrict__ in, ushort_t* __restrict__ out, int n4) {
    int i = blockIdx.x * 256 + threadIdx.x;
    if (i < n4) {
        float4 v = ((const float4*)in)[i];
        ushort4 o;
        o.x = f2bf(v.x); o.y = f2bf(v.y); o.z = f2bf(v.z); o.w = f2bf(v.w);
        ((ushort4*)out)[i] = o;
    }
}

// ---------------- mean aggregation (128-dim bf16 rows, 8-wide MLP) ----------------
__global__ void aggregate_bf(const ushort_t* __restrict__ hbf,
                             const int* __restrict__ rowstart,
                             const int* __restrict__ csr_src,
                             ushort_t* __restrict__ meanbf) {
    int node = blockIdx.x * 4 + (threadIdx.x >> 6);
    int lane = threadIdx.x & 63;
    if (node >= N_NODES) return;
    int s0 = rowstart[node], s1 = rowstart[node + 1];
    float ax = 0.f, ay = 0.f;
    const uint_t* base = (const uint_t*)hbf;
    for (int b = s0; b < s1; b += 64) {
        int m = min(64, s1 - b);
        int idx = (lane < m) ? csr_src[b + lane] : 0;
        int j = 0;
        for (; j + 8 <= m; j += 8) {
            uint_t v0 = base[(size_t)__shfl(idx, j + 0, 64) * 64 + lane];
            uint_t v1 = base[(size_t)__shfl(idx, j + 1, 64) * 64 + lane];
            uint_t v2 = base[(size_t)__shfl(idx, j + 2, 64) * 64 + lane];
            uint_t v3 = base[(size_t)__shfl(idx, j + 3, 64) * 64 + lane];
            uint_t v4 = base[(size_t)__shfl(idx, j + 4, 64) * 64 + lane];
            uint_t v5 = base[(size_t)__shfl(idx, j + 5, 64) * 64 + lane];
            uint_t v6 = base[(size_t)__shfl(idx, j + 6, 64) * 64 + lane];
            uint_t v7 = base[(size_t)__shfl(idx, j + 7, 64) * 64 + lane];
            ax += ((bflo(v0) + bflo(v1)) + (bflo(v2) + bflo(v3)))
                + ((bflo(v4) + bflo(v5)) + (bflo(v6) + bflo(v7)));
            ay += ((bfhi(v0) + bfhi(v1)) + (bfhi(v2) + bfhi(v3)))
                + ((bfhi(v4) + bfhi(v5)) + (bfhi(v6) + bfhi(v7)));
        }
        for (; j + 4 <= m; j += 4) {
            uint_t v0 = base[(size_t)__shfl(idx, j + 0, 64) * 64 + lane];
            uint_t v1 = base[(size_t)__shfl(idx, j + 1, 64) * 64 + lane];
            uint_t v2 = base[(size_t)__shfl(idx, j + 2, 64) * 64 + lane];
            uint_t v3 = base[(size_t)__shfl(idx, j + 3, 64) * 64 + lane];
            ax += (bflo(v0) + bflo(v1)) + (bflo(v2) + bflo(v3));
            ay += (bfhi(v0) + bfhi(v1)) + (bfhi(v2) + bfhi(v3));
        }
        for (; j < m; ++j) {
            uint_t v = base[(size_t)__shfl(idx, j, 64) * 64 + lane];
            ax += bflo(v);
            ay += bfhi(v);
        }
    }
    float inv = 1.0f / fmaxf((float)(s1 - s0), 1.0f);
    ax *= inv; ay *= inv;
    uint_t packed = (uint_t)f2bf(ax) | ((uint_t)f2bf(ay) << 16);
    ((uint_t*)meanbf)[(size_t)node * 64 + lane] = packed;
}

// ---------------- bf16 MFMA GEMM: out = [mean|root] @ [Wl;Wr] + b, ReLU ----------------
// layers 0/1 only (DO=128). K=256 stacked. Weights transposed in LDS.
__global__ __launch_bounds__(256, 2) void sage_gemm_mfma(
    const ushort_t* __restrict__ mean_bf, const ushort_t* __restrict__ root_bf,
    const float* __restrict__ Wl, const float* __restrict__ Wr,
    const float* __restrict__ bias, ushort_t* __restrict__ out_bf) {
    constexpr int DO = 128, NT = 8;
    __shared__ ushort_t Wt[DO][264];

    constexpr int TOT = 256 * DO;
    for (int idx = threadIdx.x; idx < TOT; idx += 256) {
        int k = idx / DO, n = idx % DO;
        float w = (k < 128) ? Wl[k * DO + n] : Wr[(k - 128) * DO + n];
        Wt[n][k] = f2bf(w);
    }
    __syncthreads();

    int lane = threadIdx.x & 63;
    int wave = threadIdx.x >> 6;
    int row16 = lane & 15;
    int quad = lane >> 4;
    int rowBase = blockIdx.x * 64 + wave * 16;
    int arow = min(rowBase + row16, N_NODES - 1);
    const ushort_t* mrow = mean_bf + (size_t)arow * 128;
    const ushort_t* rrow = root_bf + (size_t)arow * 128;

    f32x4 acc[NT];
    #pragma unroll
    for (int t = 0; t < NT; ++t) { f32x4 z = {0.f, 0.f, 0.f, 0.f}; acc[t] = z; }

    #pragma unroll
    for (int ks = 0; ks < 8; ++ks) {
        int k0 = ks * 32;
        const ushort_t* src = (k0 < 128) ? (mrow + k0 + quad * 8)
                                         : (rrow + (k0 - 128) + quad * 8);
        short8 afrag = *(const short8*)src;
        #pragma unroll
        for (int t = 0; t < NT; ++t) {
            short8 bfrag = *(const short8*)&Wt[t * 16 + row16][k0 + quad * 8];
            acc[t] = __builtin_amdgcn_mfma_f32_16x16x32_bf16(afrag, bfrag, acc[t], 0, 0, 0);
        }
    }

    #pragma unroll
    for (int t = 0; t < NT; ++t) {
        int col = t * 16 + row16;
        float bv = bias[col];
        #pragma unroll
        for (int r = 0; r < 4; ++r) {
            int row = rowBase + quad * 4 + r;
            if (row < N_NODES) {
                float v = fmaxf(acc[t][r] + bv, 0.f);
                out_bf[(size_t)row * DO + col] = f2bf(v);
            }
        }
    }
}

// ---------------- layer-2 pre-transform: [z | r] = h @ [Wl2 | Wr2], r += b2 ----------------
__global__ __launch_bounds__(256, 2) void gemm_zr(
    const ushort_t* __restrict__ h_bf,
    const float* __restrict__ Wl, const float* __restrict__ Wr,
    const float* __restrict__ bias,
    ushort_t* __restrict__ z_bf, float* __restrict__ r_f32) {
    constexpr int NT = 8;                 // 128 output cols: 0-63 z, 64-127 r
    __shared__ ushort_t Wt[128][136];     // [n][k], K=128

    for (int idx = threadIdx.x; idx < 128 * 128; idx += 256) {
        int k = idx >> 7, n = idx & 127;
        float w = (n < 64) ? Wl[k * 64 + n] : Wr[k * 64 + (n - 64)];
        Wt[n][k] = f2bf(w);
    }
    __syncthreads();

    int lane = threadIdx.x & 63;
    int wave = threadIdx.x >> 6;
    int row16 = lane & 15;
    int quad = lane >> 4;
    int rowBase = blockIdx.x * 64 + wave * 16;
    int arow = min(rowBase + row16, N_NODES - 1);
    const ushort_t* hrow = h_bf + (size_t)arow * 128;

    f32x4 acc[NT];
    #pragma unroll
    for (int t = 0; t < NT; ++t) { f32x4 z = {0.f, 0.f, 0.f, 0.f}; acc[t] = z; }

    #pragma unroll
    for (int ks = 0; ks < 4; ++ks) {
        int k0 = ks * 32;
        short8 afrag = *(const short8*)(hrow + k0 + quad * 8);
        #pragma unroll
        for (int t = 0; t < NT; ++t) {
            short8 bfrag = *(const short8*)&Wt[t * 16 + row16][k0 + quad * 8];
            acc[t] = __builtin_amdgcn_mfma_f32_16x16x32_bf16(afrag, bfrag, acc[t], 0, 0, 0);
        }
    }

    #pragma unroll
    for (int t = 0; t < NT; ++t) {
        int col = t * 16 + row16;
        #pragma unroll
        for (int r = 0; r < 4; ++r) {
            int row = rowBase + quad * 4 + r;
            if (row < N_NODES) {
                if (col < 64) {
                    z_bf[(size_t)row * 64 + col] = f2bf(acc[t][r]);
                } else {
                    r_f32[(size_t)row * 64 + (col - 64)] = acc[t][r] + bias[col - 64];
                }
            }
        }
    }
}

// ---------------- final: mean(z[src]) + r, log_softmax, write both outputs ----------------
__global__ void final_agg_softmax(const ushort_t* __restrict__ z_bf,
                                  const float* __restrict__ r_f32,
                                  const int* __restrict__ rowstart,
                                  const int* __restrict__ csr_src,
                                  float* __restrict__ out) {
    int node = blockIdx.x * 4 + (threadIdx.x >> 6);
    int lane = threadIdx.x & 63;
    if (node >= N_NODES) return;
    int s0 = rowstart[node], s1 = rowstart[node + 1];
    float a = 0.f;
    for (int b = s0; b < s1; b += 64) {
        int m = min(64, s1 - b);
        int idx = (lane < m) ? csr_src[b + lane] : 0;
        int j = 0;
        for (; j + 8 <= m; j += 8) {
            float v0 = bf2f(z_bf[(size_t)__shfl(idx, j + 0, 64) * 64 + lane]);
            float v1 = bf2f(z_bf[(size_t)__shfl(idx, j + 1, 64) * 64 + lane]);
            float v2 = bf2f(z_bf[(size_t)__shfl(idx, j + 2, 64) * 64 + lane]);
            float v3 = bf2f(z_bf[(size_t)__shfl(idx, j + 3, 64) * 64 + lane]);
            float v4 = bf2f(z_bf[(size_t)__shfl(idx, j + 4, 64) * 64 + lane]);
            float v5 = bf2f(z_bf[(size_t)__shfl(idx, j + 5, 64) * 64 + lane]);
            float v6 = bf2f(z_bf[(size_t)__shfl(idx, j + 6, 64) * 64 + lane]);
            float v7 = bf2f(z_bf[(size_t)__shfl(idx, j + 7, 64) * 64 + lane]);
            a += ((v0 + v1) + (v2 + v3)) + ((v4 + v5) + (v6 + v7));
        }
        for (; j < m; ++j)
            a += bf2f(z_bf[(size_t)__shfl(idx, j, 64) * 64 + lane]);
    }
    float inv = 1.0f / fmaxf((float)(s1 - s0), 1.0f);
    float h = a * inv + r_f32[(size_t)node * 64 + lane];
    float mx = h;
    for (int off = 32; off; off >>= 1) mx = fmaxf(mx, __shfl_xor(mx, off, 64));
    float e = expf(h - mx);
    float s = e;
    for (int off = 32; off; off >>= 1) s += __shfl_xor(s, off, 64);
    float lse = mx + logf(s);
    out[(size_t)node * 64 + lane] = h - lse;                               // log_softmax
    out[(size_t)N_NODES * 64 + (size_t)node * 64 + lane] = h;              // h
}

extern "C" void kernel_launch(void* const* d_in, const int* in_sizes, int n_in,
                              void* d_out, int out_size, void* d_ws, size_t ws_size,
                              hipStream_t stream) {
    const float* x  = (const float*)d_in[0];
    const int* ei   = (const int*)d_in[1];
    const float* Wl0 = (const float*)d_in[2];
    const float* Wr0 = (const float*)d_in[3];
    const float* b0  = (const float*)d_in[4];
    const float* Wl1 = (const float*)d_in[5];
    const float* Wr1 = (const float*)d_in[6];
    const float* b1  = (const float*)d_in[7];
    const float* Wl2 = (const float*)d_in[8];
    const float* Wr2 = (const float*)d_in[9];
    const float* b2  = (const float*)d_in[10];
    float* out = (float*)d_out;

    char* ws = (char*)d_ws;
    int* cnt      = (int*)(ws + 0x000000);
    int* rowstart = (int*)(ws + 0x040000);
    int* cursor   = (int*)(ws + 0x080000);
    int* bsum     = (int*)(ws + 0x0C0000);
    int* bprefix  = (int*)(ws + 0x0C1000);
    int* csr_src  = (int*)(ws + 0x100000);
    ushort_t* x_bf    = (ushort_t*)(ws + 0x0500000);  // 12.8 MB; dead after gemm layer 0
    ushort_t* mean_bf = (ushort_t*)(ws + 0x1200000);  // 12.8 MB; dead after gemm layer 1
    ushort_t* h_bf    = (ushort_t*)(ws + 0x1F00000);  // 12.8 MB
    ushort_t* z_bf    = (ushort_t*)(ws + 0x1200000);  // 6.4 MB, aliases mean_bf (dead)
    float*    r_f32   = (float*)  (ws + 0x0500000);   // 12.8 MB, aliases x_bf (dead)

    // ---- CSR build (XCD-windowed counting sort) ----
    hipMemsetAsync(cnt, 0, N_NODES * sizeof(int), stream);
    count_edges_mp<<<1024, 256, 0, stream>>>(ei, cnt);
    block_sums<<<SCAN_BLOCKS, 256, 0, stream>>>(cnt, bsum);
    scan_bsums<<<1, 256, 0, stream>>>(bsum, bprefix, rowstart);
    apply_scan<<<SCAN_BLOCKS, 256, 0, stream>>>(cnt, bprefix, rowstart, cursor);
    fill_csr_mp<<<1024, 256, 0, stream>>>(ei, cursor, csr_src);

    // ---- x -> bf16 ----
    cvt_bf16<<<6250, 256, 0, stream>>>(x, x_bf, (N_NODES * 128) / 4);

    // ---- layer 0 ----
    aggregate_bf<<<12500, 256, 0, stream>>>(x_bf, rowstart, csr_src, mean_bf);
    sage_gemm_mfma<<<782, 256, 0, stream>>>(mean_bf, x_bf, Wl0, Wr0, b0, h_bf);

    // ---- layer 1 ----
    aggregate_bf<<<12500, 256, 0, stream>>>(h_bf, rowstart, csr_src, mean_bf);
    sage_gemm_mfma<<<782, 256, 0, stream>>>(mean_bf, h_bf, Wl1, Wr1, b1, h_bf);

    // ---- layer 2: transform-first (mean is linear), then fused agg+softmax ----
    gemm_zr<<<782, 256, 0, stream>>>(h_bf, Wl2, Wr2, b2, z_bf, r_f32);
    final_agg_softmax<<<12500, 256, 0, stream>>>(z_bf, r_f32, rowstart, csr_src, out);
}

// Round 4
// 330.733 us; speedup vs baseline: 1.8050x; 1.0761x over previous
//
#include <hip/hip_runtime.h>

#define N_NODES 50000
#define N_EDGES 800000
#define SCAN_BLOCKS 196          // ceil(50000/256)
#define WIN 6250                 // dst window per XCD group (50000/8)

typedef __attribute__((ext_vector_type(8))) short short8;
typedef __attribute__((ext_vector_type(4))) float f32x4;
typedef unsigned short ushort_t;
typedef unsigned int uint_t;

// ---------------- helpers ----------------
__device__ inline ushort_t f2bf(float f) {
    union { float f; uint_t u; } v; v.f = f;
    uint_t u = v.u;
    u += 0x7fffu + ((u >> 16) & 1u);   // RNE
    return (ushort_t)(u >> 16);
}
__device__ inline float bflo(uint_t v) { return __uint_as_float(v << 16); }
__device__ inline float bfhi(uint_t v) { return __uint_as_float(v & 0xffff0000u); }
__device__ inline float bf2f(ushort_t v) { return __uint_as_float((uint_t)v << 16); }

// ---------------- CSR build: XCD-windowed counting sort ----------------
__global__ void count_edges_mp(const int* __restrict__ ei, int* __restrict__ cnt) {
    int g = blockIdx.x & 7;
    int nb = gridDim.x >> 3;
    int bi = blockIdx.x >> 3;
    int lo = g * WIN;
    for (int e = bi * 256 + threadIdx.x; e < N_EDGES; e += nb * 256) {
        int d = ei[N_EDGES + e];
        if ((unsigned)(d - lo) < WIN) atomicAdd(&cnt[d], 1);
    }
}

__global__ void fill_csr_mp(const int* __restrict__ ei, int* __restrict__ cursor,
                            int* __restrict__ csr_src) {
    int g = blockIdx.x & 7;
    int nb = gridDim.x >> 3;
    int bi = blockIdx.x >> 3;
    int lo = g * WIN;
    for (int e = bi * 256 + threadIdx.x; e < N_EDGES; e += nb * 256) {
        int d = ei[N_EDGES + e];
        if ((unsigned)(d - lo) < WIN) {
            int p = atomicAdd(&cursor[d], 1);
            csr_src[p] = ei[e];
        }
    }
}

__global__ void block_sums(const int* __restrict__ cnt, int* __restrict__ bsum) {
    int i = blockIdx.x * 256 + threadIdx.x;
    int v = (i < N_NODES) ? cnt[i] : 0;
    for (int off = 32; off; off >>= 1) v += __shfl_down(v, off, 64);
    __shared__ int s[4];
    if ((threadIdx.x & 63) == 0) s[threadIdx.x >> 6] = v;
    __syncthreads();
    if (threadIdx.x == 0) bsum[blockIdx.x] = s[0] + s[1] + s[2] + s[3];
}

__global__ void scan_bsums(const int* __restrict__ bsum, int* __restrict__ bprefix,
                           int* __restrict__ rowstart) {
    __shared__ int s[256];
    int t = threadIdx.x;
    int v = (t < SCAN_BLOCKS) ? bsum[t] : 0;
    s[t] = v;
    __syncthreads();
    for (int off = 1; off < 256; off <<= 1) {
        int add = (t >= off) ? s[t - off] : 0;
        __syncthreads();
        s[t] += add;
        __syncthreads();
    }
    bprefix[t] = s[t] - v;
    if (t == 0) rowstart[N_NODES] = N_EDGES;
}

__global__ void apply_scan(const int* __restrict__ cnt, const int* __restrict__ bprefix,
                           int* __restrict__ rowstart, int* __restrict__ cursor) {
    __shared__ int s[256];
    int t = threadIdx.x;
    int i = blockIdx.x * 256 + t;
    int v = (i < N_NODES) ? cnt[i] : 0;
    s[t] = v;
    __syncthreads();
    for (int off = 1; off < 256; off <<= 1) {
        int add = (t >= off) ? s[t - off] : 0;
        __syncthreads();
        s[t] += add;
        __syncthreads();
    }
    int excl = s[t] - v + bprefix[blockIdx.x];
    if (i < N_NODES) { rowstart[i] = excl; cursor[i] = excl; }
}

// ---------------- fp32 -> bf16 conversion (x only) ----------------
__global__ void cvt_bf16(const float* __restrict__ in, ushort_t* __restrict__ out, int n4) {
    int i = blockIdx.x * 256 + threadIdx.x;
    if (i < n4) {
        float4 v = ((const float4*)in)[i];
        ushort4 o;
        o.x = f2bf(v.x); o.y = f2bf(v.y); o.z = f2bf(v.z); o.w = f2bf(v.w);
        ((ushort4*)out)[i] = o;
    }
}

// ---------------- weight pre-pack into MFMA B-fragment order ----------------
// elem (ks,t,lane,j) -> offset ((ks*8+t)*64+lane)*8+j ; B[n][k]: n=t*16+(lane&15),
// k=ks*32+(lane>>4)*8+j. One wave's (ks,t) fragment = contiguous 1KB.
__global__ void pack_w256(const float* __restrict__ Wl, const float* __restrict__ Wr,
                          ushort_t* __restrict__ out) {
    int idx = blockIdx.x * 256 + threadIdx.x;       // 32768 total
    if (idx >= 8 * 8 * 64 * 8) return;
    int j = idx & 7, l = (idx >> 3) & 63, t = (idx >> 9) & 7, ks = idx >> 12;
    int n = t * 16 + (l & 15);
    int k = ks * 32 + (l >> 4) * 8 + j;
    float w = (k < 128) ? Wl[k * 128 + n] : Wr[(k - 128) * 128 + n];
    out[idx] = f2bf(w);
}

// layer-2 combined [Wl2 | Wr2]: 128 out-cols (0-63 z, 64-127 r), K=128 (4 ks)
__global__ void pack_wzr(const float* __restrict__ Wl, const float* __restrict__ Wr,
                         ushort_t* __restrict__ out) {
    int idx = blockIdx.x * 256 + threadIdx.x;       // 16384 total
    if (idx >= 4 * 8 * 64 * 8) return;
    int j = idx & 7, l = (idx >> 3) & 63, t = (idx >> 9) & 7, ks = idx >> 12;
    int n = t * 16 + (l & 15);
    int k = ks * 32 + (l >> 4) * 8 + j;
    float w = (n < 64) ? Wl[k * 64 + n] : Wr[k * 64 + (n - 64)];
    out[idx] = f2bf(w);
}

// ---------------- mean aggregation (128-dim bf16 rows, 8-wide MLP) ----------------
__global__ void aggregate_bf(const ushort_t* __restrict__ hbf,
                             const int* __restrict__ rowstart,
                             const int* __restrict__ csr_src,
                             ushort_t* __restrict__ meanbf) {
    int node = blockIdx.x * 4 + (threadIdx.x >> 6);
    int lane = threadIdx.x & 63;
    if (node >= N_NODES) return;
    int s0 = rowstart[node], s1 = rowstart[node + 1];
    float ax = 0.f, ay = 0.f;
    const uint_t* base = (const uint_t*)hbf;
    for (int b = s0; b < s1; b += 64) {
        int m = min(64, s1 - b);
        int idx = (lane < m) ? csr_src[b + lane] : 0;
        int j = 0;
        for (; j + 8 <= m; j += 8) {
            uint_t v0 = base[(size_t)__shfl(idx, j + 0, 64) * 64 + lane];
            uint_t v1 = base[(size_t)__shfl(idx, j + 1, 64) * 64 + lane];
            uint_t v2 = base[(size_t)__shfl(idx, j + 2, 64) * 64 + lane];
            uint_t v3 = base[(size_t)__shfl(idx, j + 3, 64) * 64 + lane];
            uint_t v4 = base[(size_t)__shfl(idx, j + 4, 64) * 64 + lane];
            uint_t v5 = base[(size_t)__shfl(idx, j + 5, 64) * 64 + lane];
            uint_t v6 = base[(size_t)__shfl(idx, j + 6, 64) * 64 + lane];
            uint_t v7 = base[(size_t)__shfl(idx, j + 7, 64) * 64 + lane];
            ax += ((bflo(v0) + bflo(v1)) + (bflo(v2) + bflo(v3)))
                + ((bflo(v4) + bflo(v5)) + (bflo(v6) + bflo(v7)));
            ay += ((bfhi(v0) + bfhi(v1)) + (bfhi(v2) + bfhi(v3)))
                + ((bfhi(v4) + bfhi(v5)) + (bfhi(v6) + bfhi(v7)));
        }
        for (; j < m; ++j) {
            uint_t v = base[(size_t)__shfl(idx, j, 64) * 64 + lane];
            ax += bflo(v);
            ay += bfhi(v);
        }
    }
    float inv = 1.0f / fmaxf((float)(s1 - s0), 1.0f);
    ax *= inv; ay *= inv;
    uint_t packed = (uint_t)f2bf(ax) | ((uint_t)f2bf(ay) << 16);
    ((uint_t*)meanbf)[(size_t)node * 64 + lane] = packed;
}

// ---------------- bf16 MFMA GEMM (pre-packed B, no LDS): h = relu([mean|root]@[Wl;Wr]+b) ----------------
__global__ __launch_bounds__(256) void sage_gemm_pk(
    const ushort_t* __restrict__ mean_bf, const ushort_t* __restrict__ root_bf,
    const ushort_t* __restrict__ Bpk, const float* __restrict__ bias,
    ushort_t* __restrict__ out_bf) {
    int lane = threadIdx.x & 63;
    int wave = threadIdx.x >> 6;
    int row16 = lane & 15;
    int quad = lane >> 4;
    int rowBase = blockIdx.x * 64 + wave * 16;
    int arow = min(rowBase + row16, N_NODES - 1);
    const ushort_t* mrow = mean_bf + (size_t)arow * 128;
    const ushort_t* rrow = root_bf + (size_t)arow * 128;
    const short8* bp = (const short8*)Bpk + lane;

    f32x4 acc[8];
    #pragma unroll
    for (int t = 0; t < 8; ++t) { f32x4 z = {0.f, 0.f, 0.f, 0.f}; acc[t] = z; }

    #pragma unroll
    for (int ks = 0; ks < 8; ++ks) {
        const ushort_t* src = (ks < 4) ? (mrow + ks * 32 + quad * 8)
                                       : (rrow + (ks - 4) * 32 + quad * 8);
        short8 afrag = *(const short8*)src;
        #pragma unroll
        for (int t = 0; t < 8; ++t) {
            short8 bfrag = bp[(ks * 8 + t) * 64];
            acc[t] = __builtin_amdgcn_mfma_f32_16x16x32_bf16(afrag, bfrag, acc[t], 0, 0, 0);
        }
    }

    #pragma unroll
    for (int t = 0; t < 8; ++t) {
        int col = t * 16 + row16;
        float bv = bias[col];
        #pragma unroll
        for (int r = 0; r < 4; ++r) {
            int row = rowBase + quad * 4 + r;
            if (row < N_NODES) {
                float v = fmaxf(acc[t][r] + bv, 0.f);
                out_bf[(size_t)row * 128 + col] = f2bf(v);
            }
        }
    }
}

// ---------------- layer-2 pre-transform (pre-packed B): [z | r] = h @ [Wl2 | Wr2], r += b2 ----------------
__global__ __launch_bounds__(256) void gemm_zr_pk(
    const ushort_t* __restrict__ h_bf, const ushort_t* __restrict__ Bpk,
    const float* __restrict__ bias,
    ushort_t* __restrict__ z_bf, float* __restrict__ r_f32) {
    int lane = threadIdx.x & 63;
    int wave = threadIdx.x >> 6;
    int row16 = lane & 15;
    int quad = lane >> 4;
    int rowBase = blockIdx.x * 64 + wave * 16;
    int arow = min(rowBase + row16, N_NODES - 1);
    const ushort_t* hrow = h_bf + (size_t)arow * 128;
    const short8* bp = (const short8*)Bpk + lane;

    f32x4 acc[8];
    #pragma unroll
    for (int t = 0; t < 8; ++t) { f32x4 z = {0.f, 0.f, 0.f, 0.f}; acc[t] = z; }

    #pragma unroll
    for (int ks = 0; ks < 4; ++ks) {
        short8 afrag = *(const short8*)(hrow + ks * 32 + quad * 8);
        #pragma unroll
        for (int t = 0; t < 8; ++t) {
            short8 bfrag = bp[(ks * 8 + t) * 64];
            acc[t] = __builtin_amdgcn_mfma_f32_16x16x32_bf16(afrag, bfrag, acc[t], 0, 0, 0);
        }
    }

    #pragma unroll
    for (int t = 0; t < 8; ++t) {
        int col = t * 16 + row16;
        #pragma unroll
        for (int r = 0; r < 4; ++r) {
            int row = rowBase + quad * 4 + r;
            if (row < N_NODES) {
                if (col < 64) {
                    z_bf[(size_t)row * 64 + col] = f2bf(acc[t][r]);
                } else {
                    r_f32[(size_t)row * 64 + (col - 64)] = acc[t][r] + bias[col - 64];
                }
            }
        }
    }
}

// ---------------- final: mean(z[src]) + r, log_softmax, write both outputs ----------------
__global__ void final_agg_softmax(const ushort_t* __restrict__ z_bf,
                                  const float* __restrict__ r_f32,
                                  const int* __restrict__ rowstart,
                                  const int* __restrict__ csr_src,
                                  float* __restrict__ out) {
    int node = blockIdx.x * 4 + (threadIdx.x >> 6);
    int lane = threadIdx.x & 63;
    if (node >= N_NODES) return;
    int s0 = rowstart[node], s1 = rowstart[node + 1];
    float a = 0.f;
    for (int b = s0; b < s1; b += 64) {
        int m = min(64, s1 - b);
        int idx = (lane < m) ? csr_src[b + lane] : 0;
        int j = 0;
        for (; j + 8 <= m; j += 8) {
            float v0 = bf2f(z_bf[(size_t)__shfl(idx, j + 0, 64) * 64 + lane]);
            float v1 = bf2f(z_bf[(size_t)__shfl(idx, j + 1, 64) * 64 + lane]);
            float v2 = bf2f(z_bf[(size_t)__shfl(idx, j + 2, 64) * 64 + lane]);
            float v3 = bf2f(z_bf[(size_t)__shfl(idx, j + 3, 64) * 64 + lane]);
            float v4 = bf2f(z_bf[(size_t)__shfl(idx, j + 4, 64) * 64 + lane]);
            float v5 = bf2f(z_bf[(size_t)__shfl(idx, j + 5, 64) * 64 + lane]);
            float v6 = bf2f(z_bf[(size_t)__shfl(idx, j + 6, 64) * 64 + lane]);
            float v7 = bf2f(z_bf[(size_t)__shfl(idx, j + 7, 64) * 64 + lane]);
            a += ((v0 + v1) + (v2 + v3)) + ((v4 + v5) + (v6 + v7));
        }
        for (; j < m; ++j)
            a += bf2f(z_bf[(size_t)__shfl(idx, j, 64) * 64 + lane]);
    }
    float inv = 1.0f / fmaxf((float)(s1 - s0), 1.0f);
    float h = a * inv + r_f32[(size_t)node * 64 + lane];
    float mx = h;
    for (int off = 32; off; off >>= 1) mx = fmaxf(mx, __shfl_xor(mx, off, 64));
    float e = expf(h - mx);
    float s = e;
    for (int off = 32; off; off >>= 1) s += __shfl_xor(s, off, 64);
    float lse = mx + logf(s);
    out[(size_t)node * 64 + lane] = h - lse;                               // log_softmax
    out[(size_t)N_NODES * 64 + (size_t)node * 64 + lane] = h;              // h
}

extern "C" void kernel_launch(void* const* d_in, const int* in_sizes, int n_in,
                              void* d_out, int out_size, void* d_ws, size_t ws_size,
                              hipStream_t stream) {
    const float* x  = (const float*)d_in[0];
    const int* ei   = (const int*)d_in[1];
    const float* Wl0 = (const float*)d_in[2];
    const float* Wr0 = (const float*)d_in[3];
    const float* b0  = (const float*)d_in[4];
    const float* Wl1 = (const float*)d_in[5];
    const float* Wr1 = (const float*)d_in[6];
    const float* b1  = (const float*)d_in[7];
    const float* Wl2 = (const float*)d_in[8];
    const float* Wr2 = (const float*)d_in[9];
    const float* b2  = (const float*)d_in[10];
    float* out = (float*)d_out;

    char* ws = (char*)d_ws;
    int* cnt      = (int*)(ws + 0x000000);
    int* rowstart = (int*)(ws + 0x040000);
    int* cursor   = (int*)(ws + 0x080000);
    int* bsum     = (int*)(ws + 0x0C0000);
    int* bprefix  = (int*)(ws + 0x0C1000);
    int* csr_src  = (int*)(ws + 0x100000);            // 3.2 MB, ends 0x40D400
    ushort_t* pk0 = (ushort_t*)(ws + 0x420000);       // 64 KB
    ushort_t* pk1 = (ushort_t*)(ws + 0x440000);       // 64 KB
    ushort_t* pkz = (ushort_t*)(ws + 0x460000);       // 32 KB
    ushort_t* x_bf    = (ushort_t*)(ws + 0x0500000);  // 12.8 MB; dead after gemm layer 0
    ushort_t* mean_bf = (ushort_t*)(ws + 0x1200000);  // 12.8 MB; dead after gemm layer 1
    ushort_t* h_bf    = (ushort_t*)(ws + 0x1F00000);  // 12.8 MB
    ushort_t* z_bf    = (ushort_t*)(ws + 0x1200000);  // 6.4 MB, aliases mean_bf (dead)
    float*    r_f32   = (float*)  (ws + 0x0500000);   // 12.8 MB, aliases x_bf (dead)

    // ---- weight pre-pack (tiny; overlaps CSR build) ----
    pack_w256<<<128, 256, 0, stream>>>(Wl0, Wr0, pk0);
    pack_w256<<<128, 256, 0, stream>>>(Wl1, Wr1, pk1);
    pack_wzr<<<64, 256, 0, stream>>>(Wl2, Wr2, pkz);

    // ---- CSR build (XCD-windowed counting sort) ----
    hipMemsetAsync(cnt, 0, N_NODES * sizeof(int), stream);
    count_edges_mp<<<1024, 256, 0, stream>>>(ei, cnt);
    block_sums<<<SCAN_BLOCKS, 256, 0, stream>>>(cnt, bsum);
    scan_bsums<<<1, 256, 0, stream>>>(bsum, bprefix, rowstart);
    apply_scan<<<SCAN_BLOCKS, 256, 0, stream>>>(cnt, bprefix, rowstart, cursor);
    fill_csr_mp<<<1024, 256, 0, stream>>>(ei, cursor, csr_src);

    // ---- x -> bf16 ----
    cvt_bf16<<<6250, 256, 0, stream>>>(x, x_bf, (N_NODES * 128) / 4);

    // ---- layer 0 ----
    aggregate_bf<<<12500, 256, 0, stream>>>(x_bf, rowstart, csr_src, mean_bf);
    sage_gemm_pk<<<782, 256, 0, stream>>>(mean_bf, x_bf, pk0, b0, h_bf);

    // ---- layer 1 ----
    aggregate_bf<<<12500, 256, 0, stream>>>(h_bf, rowstart, csr_src, mean_bf);
    sage_gemm_pk<<<782, 256, 0, stream>>>(mean_bf, h_bf, pk1, b1, h_bf);

    // ---- layer 2: transform-first (mean is linear), then fused agg+softmax ----
    gemm_zr_pk<<<782, 256, 0, stream>>>(h_bf, pkz, b2, z_bf, r_f32);
    final_agg_softmax<<<12500, 256, 0, stream>>>(z_bf, r_f32, rowstart, csr_src, out);
}